// Round 1
// 1607.539 us; speedup vs baseline: 3.7364x; 3.7364x over previous
//
#include <hip/hip_runtime.h>
#include <hip/hip_bf16.h>

typedef __bf16 bf16_t;
typedef __bf16 bf16x4 __attribute__((ext_vector_type(4)));
typedef __bf16 bf16x8 __attribute__((ext_vector_type(8)));
typedef float f32x4 __attribute__((ext_vector_type(4)));

#define B_ 2
#define S_ 2048
#define HID_ 5120
#define H_ 32
#define D_NOPE_ 128
#define D_ROPE_ 64
#define D_V_ 128
#define D_Q_ 192
#define EPS_ 1e-6f

// ---------------------------------------------------------------------------
// fp32 -> bf16 cast, 8 elems/thread. n must be divisible by 2048 (all are).
// ---------------------------------------------------------------------------
__global__ __launch_bounds__(256) void f32_to_bf16_k(const float* __restrict__ x,
                                                     bf16_t* __restrict__ y, long n) {
  long i = ((long)blockIdx.x * 256 + threadIdx.x) * 8;
  if (i + 8 <= n) {
    float4 f0 = *(const float4*)(x + i);
    float4 f1 = *(const float4*)(x + i + 4);
    bf16x8 o;
    o[0] = (bf16_t)f0.x; o[1] = (bf16_t)f0.y; o[2] = (bf16_t)f0.z; o[3] = (bf16_t)f0.w;
    o[4] = (bf16_t)f1.x; o[5] = (bf16_t)f1.y; o[6] = (bf16_t)f1.z; o[7] = (bf16_t)f1.w;
    *(bf16x8*)(y + i) = o;
  }
}

// ---------------------------------------------------------------------------
// GEMM: C[M,N] = A[M,K] @ W[N,K]^T.  fp32 MFMA accumulate.
// A32: A is fp32 (converted to bf16 during LDS staging); else bf16.
// CMODE: 0 = bf16 C;  1 = fp32 C;  2 = split-kv epilogue:
//   n -> (h = n/256, c = n%256); c<128 -> knope[B,S,H,128] (Cv);
//   c>=128 -> vT[B,H,128,S] (vTp), i.e. V stored transposed for flash PV.
// 64x64 tile, BK=32, 256 threads (4 waves 2x2), mfma_f32_16x16x32_bf16.
// A-frag: A[m=lane&15][k=(lane>>4)*8+j]; B-frag: W[n=lane&15][k=...];
// D: col=lane&15 (=n), row=(lane>>4)*4+reg (=m)   (HW-verified layouts)
// ---------------------------------------------------------------------------
template <int A32, int CMODE>
__global__ __launch_bounds__(256) void gemm_bt(const void* __restrict__ Av,
                                               const bf16_t* __restrict__ W,
                                               void* __restrict__ Cv,
                                               bf16_t* __restrict__ vTp,
                                               int M, int N, int K) {
  __shared__ bf16_t As[64 * 40];  // stride 40 elems = 80B (16B-aligned rows)
  __shared__ bf16_t Ws[64 * 40];
  const int tid = threadIdx.x;
  const int bm = blockIdx.y * 64;
  const int bn = blockIdx.x * 64;
  const int wave = tid >> 6, lane = tid & 63;
  const int wm = (wave >> 1) * 32, wn = (wave & 1) * 32;
  const int srow = tid >> 2;
  const int scol = (tid & 3) * 8;
  const float*  Ap32 = (const float*)Av  + (size_t)(bm + srow) * K + scol;
  const bf16_t* Ap16 = (const bf16_t*)Av + (size_t)(bm + srow) * K + scol;
  const bf16_t* Wp = W + (size_t)(bn + srow) * K + scol;
  f32x4 acc00 = {}, acc01 = {}, acc10 = {}, acc11 = {};
  const int r = lane & 15;
  const int kq = (lane >> 4) * 8;
  for (int k0 = 0; k0 < K; k0 += 32) {
    if (A32) {
      float4 f0 = *(const float4*)(Ap32 + k0);
      float4 f1 = *(const float4*)(Ap32 + k0 + 4);
      bf16x8 a;
      a[0] = (bf16_t)f0.x; a[1] = (bf16_t)f0.y; a[2] = (bf16_t)f0.z; a[3] = (bf16_t)f0.w;
      a[4] = (bf16_t)f1.x; a[5] = (bf16_t)f1.y; a[6] = (bf16_t)f1.z; a[7] = (bf16_t)f1.w;
      *(bf16x8*)&As[srow * 40 + scol] = a;
    } else {
      *(bf16x8*)&As[srow * 40 + scol] = *(const bf16x8*)(Ap16 + k0);
    }
    *(bf16x8*)&Ws[srow * 40 + scol] = *(const bf16x8*)(Wp + k0);
    __syncthreads();
    bf16x8 a0 = *(bf16x8*)&As[(wm + r) * 40 + kq];
    bf16x8 a1 = *(bf16x8*)&As[(wm + 16 + r) * 40 + kq];
    bf16x8 b0 = *(bf16x8*)&Ws[(wn + r) * 40 + kq];
    bf16x8 b1 = *(bf16x8*)&Ws[(wn + 16 + r) * 40 + kq];
    acc00 = __builtin_amdgcn_mfma_f32_16x16x32_bf16(a0, b0, acc00, 0, 0, 0);
    acc01 = __builtin_amdgcn_mfma_f32_16x16x32_bf16(a0, b1, acc01, 0, 0, 0);
    acc10 = __builtin_amdgcn_mfma_f32_16x16x32_bf16(a1, b0, acc10, 0, 0, 0);
    acc11 = __builtin_amdgcn_mfma_f32_16x16x32_bf16(a1, b1, acc11, 0, 0, 0);
    __syncthreads();
  }
  const int col = lane & 15;
  const int rb = (lane >> 4) * 4;
  if constexpr (CMODE == 2) {
    bf16_t* KN = (bf16_t*)Cv;
    const int m0 = bm + wm + rb;
    auto stkv = [&](int mrow, int nn, f32x4 a) {
      int hh = nn >> 8, cc = nn & 255;
      if (cc < 128) {
        bf16_t* p = KN + ((size_t)mrow * H_ + hh) * 128 + cc;
#pragma unroll
        for (int rr = 0; rr < 4; rr++) p[(size_t)rr * (H_ * 128)] = (bf16_t)a[rr];
      } else {
        int bb = mrow >> 11;         // / S_
        int s0 = mrow & 2047;        // % S_
        bf16x4 o;
        o[0] = (bf16_t)a[0]; o[1] = (bf16_t)a[1];
        o[2] = (bf16_t)a[2]; o[3] = (bf16_t)a[3];
        *(bf16x4*)(vTp + (((size_t)bb * H_ + hh) * 128 + (cc - 128)) * S_ + s0) = o;
      }
    };
    stkv(m0, bn + wn + col, acc00);
    stkv(m0, bn + wn + 16 + col, acc01);
    stkv(m0 + 16, bn + wn + col, acc10);
    stkv(m0 + 16, bn + wn + 16 + col, acc11);
  } else {
#pragma unroll
    for (int rr = 0; rr < 4; rr++) {
      int m0r = bm + wm + rb + rr;
      int m1r = m0r + 16;
      if (CMODE == 1) {
        float* C = (float*)Cv;
        C[(size_t)m0r * N + (bn + wn + col)]      = acc00[rr];
        C[(size_t)m0r * N + (bn + wn + 16 + col)] = acc01[rr];
        C[(size_t)m1r * N + (bn + wn + col)]      = acc10[rr];
        C[(size_t)m1r * N + (bn + wn + 16 + col)] = acc11[rr];
      } else {
        bf16_t* C = (bf16_t*)Cv;
        C[(size_t)m0r * N + (bn + wn + col)]      = (bf16_t)acc00[rr];
        C[(size_t)m0r * N + (bn + wn + 16 + col)] = (bf16_t)acc01[rr];
        C[(size_t)m1r * N + (bn + wn + col)]      = (bf16_t)acc10[rr];
        C[(size_t)m1r * N + (bn + wn + 16 + col)] = (bf16_t)acc11[rr];
      }
    }
  }
}

// ---------------------------------------------------------------------------
// RMSNorm (bf16 in/out, fp32 math). w is fp32 (original input weight).
// ---------------------------------------------------------------------------
__global__ __launch_bounds__(256) void rmsnorm_k(const bf16_t* __restrict__ x,
                                                 const float* __restrict__ w,
                                                 bf16_t* __restrict__ y,
                                                 int dim, int xstride) {
  const int row = blockIdx.x;
  const bf16_t* xr = x + (size_t)row * xstride;
  bf16_t* yr = y + (size_t)row * dim;
  float ss = 0.f;
  for (int i = threadIdx.x; i < dim; i += 256) {
    float v = (float)xr[i];
    ss += v * v;
  }
  for (int off = 32; off > 0; off >>= 1) ss += __shfl_down(ss, off);
  __shared__ float red[4];
  __shared__ float s_rinv;
  if ((threadIdx.x & 63) == 0) red[threadIdx.x >> 6] = ss;
  __syncthreads();
  if (threadIdx.x == 0) {
    float tot = red[0] + red[1] + red[2] + red[3];
    s_rinv = 1.0f / sqrtf(tot / (float)dim + EPS_);
  }
  __syncthreads();
  float rinv = s_rinv;
  for (int i = threadIdx.x; i < dim; i += 256)
    yr[i] = (bf16_t)((float)xr[i] * rinv * w[i]);
}

// ---------------------------------------------------------------------------
// RoPE with deinterleave. One 64-thread block per 64-elem rope row.
// ---------------------------------------------------------------------------
__global__ __launch_bounds__(64) void rope_k(const bf16_t* __restrict__ src,
                                             bf16_t* __restrict__ dst,
                                             const int* __restrict__ pos_ids,
                                             int heads_per_pos, int sstride,
                                             int dstride) {
  __shared__ float xs[64];
  const int rrow = blockIdx.x;
  const int j = threadIdx.x;
  const bf16_t* s = src + (size_t)rrow * sstride;
  xs[j] = (float)s[j];
  __syncthreads();
  const int pos = pos_ids[rrow / heads_per_pos];
  const int i = j & 31;
  float freq = powf(10000.0f, -(float)i / 32.0f);
  float ang = (float)pos * freq;
  float c = cosf(ang), sn = sinf(ang);
  float outv;
  if (j < 32)
    outv = xs[2 * j] * c - xs[2 * j + 1] * sn;
  else
    outv = xs[2 * i + 1] * c + xs[2 * i] * sn;
  dst[(size_t)rrow * dstride + j] = (bf16_t)outv;
}

// ---------------------------------------------------------------------------
// MFMA causal flash attention.
// Block = 256 thr (4 waves). Q-block = 128 rows (wave w owns rows 32w..32w+31,
// two 16-row subtiles qs). K-tile = 64. mfma_f32_16x16x32_bf16 throughout.
//
// QK^T computed SWAPPED: St[kv][q] = mfma(A=K-frag, B=Q-frag) so both operands
// are contraction(k)-fast (no transpose). D-layout: lane holds
// St[kv=16t+4*(l>>4)+r][q=l&15] -> row-softmax reduces with shfl_xor(16,32).
// PV: O[q][d] = mfma(A=P-frag, B=V-frag) with V staged from vT[B,H,128,S]
// (produced transposed by the kv_b GEMM epilogue) so V-frag is kv-fast.
//
// LDS layouts are FRAGMENT-MAJOR ([tile][kstep][g][ll][8]): every frag read
// and staging write is byte 16*lane sequential -> bank-conflict-free b128.
// P crosses the D-layout->A-frag lane redistribution via a 2KB/wave LDS buf.
// Next K/V tile is prefetched to registers before compute (latency hiding).
// ---------------------------------------------------------------------------
__global__ __launch_bounds__(256, 2) void flash_attn2(
    const bf16_t* __restrict__ q, const bf16_t* __restrict__ knope,
    const bf16_t* __restrict__ kpe, const bf16_t* __restrict__ vT,
    bf16_t* __restrict__ attn) {
  __shared__ bf16_t KF[12288];  // [t:4][ks:6][g:4][ll:16][j:8]  24KB
  __shared__ bf16_t VF[8192];   // [dt:8][ks2:2][g:4][ll:16][j:8] 16KB
  __shared__ bf16_t PF[8192];   // per-wave 2048: [qs:2][ks2:2][g:4][ll:16][j:8]
  const int tid = threadIdx.x;
  const int w = tid >> 6;
  const int lane = tid & 63;
  const int ll = lane & 15;
  const int g0 = lane >> 4;
  const int bh = blockIdx.y;
  const int b = bh >> 5;   // / H_
  const int h = bh & 31;   // % H_
  const int q0 = ((int)gridDim.x - 1 - (int)blockIdx.x) * 128;  // heavy blocks first
  const int bS = b * S_;
  bf16_t* PFw = PF + w * 2048;

  // Q fragments in registers (one-time load):
  // qf[qs][ks] = Q[q0+32w+16qs+ll][32ks+8g0 .. +7]
  bf16x8 qf[2][6];
#pragma unroll
  for (int qs = 0; qs < 2; qs++)
#pragma unroll
    for (int ks = 0; ks < 6; ks++)
      qf[qs][ks] = *(const bf16x8*)(
          q + (((size_t)(bS + q0 + 32 * w + 16 * qs + ll)) * H_ + h) * D_Q_ +
          32 * ks + 8 * g0);

  f32x4 acc[2][8];
#pragma unroll
  for (int qs = 0; qs < 2; qs++)
#pragma unroll
    for (int dt = 0; dt < 8; dt++) acc[qs][dt] = {};
  float m_run[2] = {-1e30f, -1e30f};
  float l_run[2] = {0.f, 0.f};

  // Hoisted staging pointers (k-tile-independent part).
  const bf16_t* kptr[6];
  int kstr[6];
#pragma unroll
  for (int i = 0; i < 6; i++) {
    int c = tid + 256 * i;
    int t_ = c / 384;
    int rem = c - t_ * 384;
    int ks_ = rem >> 6;
    int g_ = (rem >> 4) & 3;
    int ll_ = c & 15;
    int row = 16 * t_ + ll_;
    int k = 32 * ks_ + 8 * g_;
    if (k < 128) {
      kptr[i] = knope + ((size_t)(bS + row) * H_ + h) * 128 + k;
      kstr[i] = H_ * 128;
    } else {
      kptr[i] = kpe + (size_t)(bS + row) * 64 + (k - 128);
      kstr[i] = 64;
    }
  }
  const bf16_t* vptr[4];
#pragma unroll
  for (int i = 0; i < 4; i++) {
    int c = tid + 256 * i;
    int ll_ = c & 15;
    int g_ = (c >> 4) & 3;
    int ks2_ = (c >> 6) & 1;
    int dt_ = c >> 7;
    vptr[i] = vT + (((size_t)b * H_ + h) * 128 + 16 * dt_ + ll_) * S_ +
              32 * ks2_ + 8 * g_;
  }

  bf16x8 kst[6], vst[4];
  auto load_kv = [&]() {
#pragma unroll
    for (int i = 0; i < 6; i++) kst[i] = *(const bf16x8*)kptr[i];
#pragma unroll
    for (int i = 0; i < 4; i++) vst[i] = *(const bf16x8*)vptr[i];
#pragma unroll
    for (int i = 0; i < 6; i++) kptr[i] += (size_t)64 * kstr[i];
#pragma unroll
    for (int i = 0; i < 4; i++) vptr[i] += 64;
  };

  load_kv();  // tile 0
  const int nkt = (q0 >> 6) + 2;
  const float scale = 0.07216878364870322f;  // 192^-0.5

  for (int kt = 0; kt < nkt; kt++) {
    const int k0 = kt * 64;
    __syncthreads();  // previous tile's LDS reads done
#pragma unroll
    for (int i = 0; i < 6; i++) *(bf16x8*)&KF[(tid + 256 * i) * 8] = kst[i];
#pragma unroll
    for (int i = 0; i < 4; i++) *(bf16x8*)&VF[(tid + 256 * i) * 8] = vst[i];
    __syncthreads();
    if (kt + 1 < nkt) load_kv();  // prefetch next tile under compute

    // ---- QK^T (swapped): St[kv][q] ----
    f32x4 sv[2][4];
#pragma unroll
    for (int qs = 0; qs < 2; qs++)
#pragma unroll
      for (int t = 0; t < 4; t++) sv[qs][t] = {};
#pragma unroll
    for (int ks = 0; ks < 6; ks++) {
      bf16x8 bq0 = qf[0][ks], bq1 = qf[1][ks];
#pragma unroll
      for (int t = 0; t < 4; t++) {
        bf16x8 ak = *(bf16x8*)&KF[(t * 6 + ks) * 512 + lane * 8];
        sv[0][t] = __builtin_amdgcn_mfma_f32_16x16x32_bf16(ak, bq0, sv[0][t], 0, 0, 0);
        sv[1][t] = __builtin_amdgcn_mfma_f32_16x16x32_bf16(ak, bq1, sv[1][t], 0, 0, 0);
      }
    }

    // ---- online softmax (per q-subtile; lane owns q = ll) ----
    float alq[2];
#pragma unroll
    for (int qs = 0; qs < 2; qs++) {
      const int qg = q0 + 32 * w + 16 * qs + ll;
      float mx = m_run[qs];
#pragma unroll
      for (int t = 0; t < 4; t++)
#pragma unroll
        for (int r = 0; r < 4; r++) {
          float s = sv[qs][t][r] * scale;
          int kv = k0 + 16 * t + 4 * g0 + r;
          s = (kv > qg) ? -1e30f : s;
          sv[qs][t][r] = s;
          mx = fmaxf(mx, s);
        }
      mx = fmaxf(mx, __shfl_xor(mx, 16));
      mx = fmaxf(mx, __shfl_xor(mx, 32));
      float al = __expf(m_run[qs] - mx);
      float rs = 0.f;
#pragma unroll
      for (int t = 0; t < 4; t++) {
        bf16x4 pv;
#pragma unroll
        for (int r = 0; r < 4; r++) {
          float p = __expf(sv[qs][t][r] - mx);
          rs += p;
          pv[r] = (bf16_t)p;
        }
        // P[q=ll][kv=16t+4g0+r] -> fragment-major slot
        int elem = ((qs * 2 + (t >> 1)) * 4 + 2 * (t & 1) + (g0 >> 1)) * 128 +
                   ll * 8 + 4 * (g0 & 1);
        *(bf16x4*)&PFw[elem] = pv;
      }
      rs += __shfl_xor(rs, 16);
      rs += __shfl_xor(rs, 32);
      l_run[qs] = l_run[qs] * al + rs;
      m_run[qs] = mx;
      alq[qs] = al;
    }

    // ---- rescale O (O rows are q = 4*g0 + r; alpha held by lane 4*g0+r) ----
#pragma unroll
    for (int qs = 0; qs < 2; qs++)
#pragma unroll
      for (int r = 0; r < 4; r++) {
        float a = __shfl(alq[qs], 4 * g0 + r);
#pragma unroll
        for (int dt = 0; dt < 8; dt++) acc[qs][dt][r] *= a;
      }

    // ---- PV: O[q][d] += P @ V ----
#pragma unroll
    for (int ks2 = 0; ks2 < 2; ks2++) {
      bf16x8 ap0 = *(bf16x8*)&PFw[ks2 * 512 + lane * 8];
      bf16x8 ap1 = *(bf16x8*)&PFw[(2 + ks2) * 512 + lane * 8];
#pragma unroll
      for (int dt = 0; dt < 8; dt++) {
        bf16x8 bv = *(bf16x8*)&VF[(dt * 2 + ks2) * 512 + lane * 8];
        acc[0][dt] = __builtin_amdgcn_mfma_f32_16x16x32_bf16(ap0, bv, acc[0][dt], 0, 0, 0);
        acc[1][dt] = __builtin_amdgcn_mfma_f32_16x16x32_bf16(ap1, bv, acc[1][dt], 0, 0, 0);
      }
    }
  }

  // ---- epilogue: O[q][d] / l[q] ----
#pragma unroll
  for (int qs = 0; qs < 2; qs++) {
    float linv = 1.f / l_run[qs];
#pragma unroll
    for (int r = 0; r < 4; r++) {
      float inv = __shfl(linv, 4 * g0 + r);
      int qrow = q0 + 32 * w + 16 * qs + 4 * g0 + r;
      bf16_t* op = attn + (((size_t)(bS + qrow)) * H_ + h) * D_V_ + ll;
#pragma unroll
      for (int dt = 0; dt < 8; dt++)
        op[dt * 16] = (bf16_t)(acc[qs][dt][r] * inv);
    }
  }
}

// ---------------------------------------------------------------------------
extern "C" void kernel_launch(void* const* d_in, const int* in_sizes, int n_in,
                              void* d_out, int out_size, void* d_ws, size_t ws_size,
                              hipStream_t stream) {
  const float* hidden  = (const float*)d_in[0];   // [4096,5120] fp32
  const float* q_a_w   = (const float*)d_in[1];   // [1536,5120] fp32
  const float* q_a_ln  = (const float*)d_in[2];   // [1536] fp32
  const float* q_b_w   = (const float*)d_in[3];   // [6144,1536] fp32
  const float* kv_a_w  = (const float*)d_in[4];   // [576,5120] fp32
  const float* kv_a_ln = (const float*)d_in[5];   // [512] fp32
  const float* kv_b_w  = (const float*)d_in[6];   // [8192,512] fp32
  const float* o_w     = (const float*)d_in[7];   // [5120,4096] fp32
  const int*   pos_ids = (const int*)d_in[8];
  // d_in[9] = attention_mask (causal tril) — hardcoded in flash kernel
  float* out = (float*)d_out;                     // [4096,5120] fp32
  char* ws = (char*)d_ws;
  const int M = B_ * S_;  // 4096

  // workspace layout (bytes); Wslot reused for each converted weight;
  // attn overlaps dead transients. Peak = ~185 MB.
  bf16_t* q_ws   = (bf16_t*)(ws + 0);            // 4096x6144 bf16 (50.3MB)
  bf16_t* knope_ws=(bf16_t*)(ws + 50331648);     // [B,S,H,128] bf16 (33.6MB)
  bf16_t* vT_ws  = (bf16_t*)(ws + 83886080);     // [B,H,128,S] bf16 (33.6MB)
  bf16_t* kpe_ws = (bf16_t*)(ws + 117440512);    // 4096x64   bf16 (0.5MB)
  bf16_t* Wslot  = (bf16_t*)(ws + 117964800);    // up to 20.97M elems (41.9MB)
  bf16_t* qc_ws  = (bf16_t*)(ws + 159907840);    // 4096x1536 (12.6MB)
  bf16_t* qcn_ws = (bf16_t*)(ws + 172490752);    // 4096x1536 (12.6MB)
  bf16_t* ckv_ws = (bf16_t*)(ws + 185073664);    // 4096x576  (4.7MB)
  bf16_t* ckvn_ws= (bf16_t*)(ws + 189792256);    // 4096x512  (4.2MB) end 193986560
  bf16_t* attn_ws= (bf16_t*)(ws + 159907840);    // 4096x4096 (33.5MB) overlaps qc..ckvn

  // q_c = hidden @ q_a_w^T
  f32_to_bf16_k<<<1536 * 5120 / 2048, 256, 0, stream>>>(q_a_w, Wslot, 1536L * 5120);
  gemm_bt<1, 0><<<dim3(1536 / 64, M / 64), 256, 0, stream>>>(hidden, Wslot, qc_ws, nullptr, M, 1536, 5120);
  rmsnorm_k<<<M, 256, 0, stream>>>(qc_ws, q_a_ln, qcn_ws, 1536, 1536);
  // q = q_cn @ q_b_w^T  [b,s,h,192]
  f32_to_bf16_k<<<6144 * 1536 / 2048, 256, 0, stream>>>(q_b_w, Wslot, 6144L * 1536);
  gemm_bt<0, 0><<<dim3(6144 / 64, M / 64), 256, 0, stream>>>(qcn_ws, Wslot, q_ws, nullptr, M, 6144, 1536);
  // ckv = hidden @ kv_a_w^T  [b,s,576]
  f32_to_bf16_k<<<576 * 5120 / 2048, 256, 0, stream>>>(kv_a_w, Wslot, 576L * 5120);
  gemm_bt<1, 0><<<dim3(576 / 64, M / 64), 256, 0, stream>>>(hidden, Wslot, ckv_ws, nullptr, M, 576, 5120);
  rmsnorm_k<<<M, 256, 0, stream>>>(ckv_ws, kv_a_ln, ckvn_ws, 512, 576);
  // kv = ckv_n @ kv_b_w^T  -> knope[B,S,H,128] + vT[B,H,128,S] (split epilogue)
  f32_to_bf16_k<<<8192 * 512 / 2048, 256, 0, stream>>>(kv_b_w, Wslot, 8192L * 512);
  gemm_bt<0, 2><<<dim3(8192 / 64, M / 64), 256, 0, stream>>>(ckvn_ws, Wslot, knope_ws, vT_ws, M, 8192, 512);
  // RoPE
  rope_k<<<M * H_, 64, 0, stream>>>(q_ws + 128, q_ws + 128, pos_ids, H_, D_Q_, D_Q_);
  rope_k<<<M, 64, 0, stream>>>(ckv_ws + 512, kpe_ws, pos_ids, 1, 576, 64);
  // MFMA flash attention -> attn_ws [b,s,h,128]
  flash_attn2<<<dim3(S_ / 128, B_ * H_), 256, 0, stream>>>(q_ws, knope_ws, kpe_ws, vT_ws, attn_ws);
  // out = attn @ o_w^T  (fp32 out)
  f32_to_bf16_k<<<5120 * 4096 / 2048, 256, 0, stream>>>(o_w, Wslot, 5120L * 4096);
  gemm_bt<0, 1><<<dim3(5120 / 64, M / 64), 256, 0, stream>>>(attn_ws, Wslot, out, nullptr, M, 5120, 4096);
}

// Round 2
// 1280.805 us; speedup vs baseline: 4.6896x; 1.2551x over previous
//
#include <hip/hip_runtime.h>
#include <hip/hip_bf16.h>

typedef __bf16 bf16_t;
typedef __bf16 bf16x4 __attribute__((ext_vector_type(4)));
typedef __bf16 bf16x8 __attribute__((ext_vector_type(8)));
typedef float f32x4 __attribute__((ext_vector_type(4)));

#define B_ 2
#define S_ 2048
#define HID_ 5120
#define H_ 32
#define D_NOPE_ 128
#define D_ROPE_ 64
#define D_V_ 128
#define D_Q_ 192
#define EPS_ 1e-6f

// async global->LDS, 16B per lane, linear LDS dest (wave-uniform base + lane*16)
#define GLDS16(g, l)                                                          \
  __builtin_amdgcn_global_load_lds(                                           \
      (const __attribute__((address_space(1))) void*)(g),                     \
      (__attribute__((address_space(3))) void*)(l), 16, 0, 0)

// ---------------------------------------------------------------------------
// fp32 -> bf16 cast, 8 elems/thread. n must be divisible by 2048 (all are).
// ---------------------------------------------------------------------------
__global__ __launch_bounds__(256) void f32_to_bf16_k(const float* __restrict__ x,
                                                     bf16_t* __restrict__ y, long n) {
  long i = ((long)blockIdx.x * 256 + threadIdx.x) * 8;
  if (i + 8 <= n) {
    float4 f0 = *(const float4*)(x + i);
    float4 f1 = *(const float4*)(x + i + 4);
    bf16x8 o;
    o[0] = (bf16_t)f0.x; o[1] = (bf16_t)f0.y; o[2] = (bf16_t)f0.z; o[3] = (bf16_t)f0.w;
    o[4] = (bf16_t)f1.x; o[5] = (bf16_t)f1.y; o[6] = (bf16_t)f1.z; o[7] = (bf16_t)f1.w;
    *(bf16x8*)(y + i) = o;
  }
}

// ---------------------------------------------------------------------------
// gemm128: C[M,N] = A[M,K] @ W[N,K]^T, bf16 in, fp32 MFMA accumulate.
// m97 structure: 128x128 tile, BK=32, 256 thr (4 waves 2x2, each 64x64 =
// 4x4 16x16x32 frags), LDS staged with global_load_lds dwordx4 (linear dest),
// 2 barriers per K-step. M,N % 128 == 0, K % 32 == 0.
// CMODE: 0 = bf16 C; 1 = fp32 C; 2 = split-kv epilogue:
//   n -> (h = n/256, c = n%256); c<128 -> knope[B,S,H,128] (Cv);
//   c>=128 -> vT[B,H,128,S] (vTp) i.e. V stored transposed for flash PV.
// A-frag: A[m=lane&15][k=(lane>>4)*8+j]; B-frag: W[n=lane&15][k=...];
// D: col=lane&15 (=n), row=(lane>>4)*4+reg (=m)   (HW-verified layouts)
// ---------------------------------------------------------------------------
template <int CMODE>
__global__ __launch_bounds__(256) void gemm128(const bf16_t* __restrict__ A,
                                               const bf16_t* __restrict__ W,
                                               void* __restrict__ Cv,
                                               bf16_t* __restrict__ vTp,
                                               int M, int N, int K) {
  __shared__ bf16_t As[128 * 32];
  __shared__ bf16_t Ws[128 * 32];
  const int tid = threadIdx.x;
  const int lane = tid & 63;
  const int wave = tid >> 6;
  const int bm = blockIdx.y * 128;
  const int bn = blockIdx.x * 128;
  const int wm = (wave >> 1) * 64;
  const int wn = (wave & 1) * 64;
  const int ll = lane & 15;
  const int kg = (lane >> 4) * 8;
  // staging chunks: c = {tid, tid+256}; row = c>>2, col = (c&3)*8 ;
  // LDS linear offset c*16B == row-major [128][32] layout.
  const int r0 = tid >> 2;
  const int cc0 = (tid & 3) * 8;
  const bf16_t* Ag0 = A + (size_t)(bm + r0) * K + cc0;
  const bf16_t* Ag1 = A + (size_t)(bm + 64 + r0) * K + cc0;
  const bf16_t* Wg0 = W + (size_t)(bn + r0) * K + cc0;
  const bf16_t* Wg1 = W + (size_t)(bn + 64 + r0) * K + cc0;
  bf16_t* Al0 = &As[tid * 8];
  bf16_t* Al1 = &As[(tid + 256) * 8];
  bf16_t* Wl0 = &Ws[tid * 8];
  bf16_t* Wl1 = &Ws[(tid + 256) * 8];

  f32x4 acc[4][4];
#pragma unroll
  for (int m = 0; m < 4; m++)
#pragma unroll
    for (int n = 0; n < 4; n++) acc[m][n] = {};

  for (int k0 = 0; k0 < K; k0 += 32) {
    GLDS16(Ag0 + k0, Al0);
    GLDS16(Ag1 + k0, Al1);
    GLDS16(Wg0 + k0, Wl0);
    GLDS16(Wg1 + k0, Wl1);
    __syncthreads();  // drains vmcnt -> LDS tile ready
    bf16x8 af[4], bfr[4];
#pragma unroll
    for (int m = 0; m < 4; m++)
      af[m] = *(const bf16x8*)&As[(wm + m * 16 + ll) * 32 + kg];
#pragma unroll
    for (int n = 0; n < 4; n++)
      bfr[n] = *(const bf16x8*)&Ws[(wn + n * 16 + ll) * 32 + kg];
#pragma unroll
    for (int m = 0; m < 4; m++)
#pragma unroll
      for (int n = 0; n < 4; n++)
        acc[m][n] = __builtin_amdgcn_mfma_f32_16x16x32_bf16(af[m], bfr[n], acc[m][n], 0, 0, 0);
    __syncthreads();  // all reads done before next tile's DMA lands
  }

  const int rb = (lane >> 4) * 4;
  if constexpr (CMODE == 2) {
    bf16_t* KN = (bf16_t*)Cv;
#pragma unroll
    for (int m = 0; m < 4; m++)
#pragma unroll
      for (int n = 0; n < 4; n++) {
        int mrow = bm + wm + m * 16 + rb;
        int nn = bn + wn + n * 16 + ll;
        int hh = nn >> 8, cc = nn & 255;
        if (cc < 128) {
          bf16_t* p = KN + ((size_t)mrow * H_ + hh) * 128 + cc;
#pragma unroll
          for (int rr = 0; rr < 4; rr++)
            p[(size_t)rr * (H_ * 128)] = (bf16_t)acc[m][n][rr];
        } else {
          int bb = mrow >> 11;   // / S_
          int s0 = mrow & 2047;  // % S_
          bf16x4 o;
          o[0] = (bf16_t)acc[m][n][0]; o[1] = (bf16_t)acc[m][n][1];
          o[2] = (bf16_t)acc[m][n][2]; o[3] = (bf16_t)acc[m][n][3];
          *(bf16x4*)(vTp + (((size_t)bb * H_ + hh) * 128 + (cc - 128)) * S_ + s0) = o;
        }
      }
  } else {
#pragma unroll
    for (int m = 0; m < 4; m++)
#pragma unroll
      for (int n = 0; n < 4; n++) {
        int row = bm + wm + m * 16 + rb;
        int col = bn + wn + n * 16 + ll;
        if (CMODE == 1) {
          float* C = (float*)Cv;
#pragma unroll
          for (int rr = 0; rr < 4; rr++)
            C[(size_t)(row + rr) * N + col] = acc[m][n][rr];
        } else {
          bf16_t* C = (bf16_t*)Cv;
#pragma unroll
          for (int rr = 0; rr < 4; rr++)
            C[(size_t)(row + rr) * N + col] = (bf16_t)acc[m][n][rr];
        }
      }
  }
}

// ---------------------------------------------------------------------------
// Legacy 64x64 GEMM (used only for kv_a: N=576 not divisible by 128).
// C[M,N] = A[M,K] @ W[N,K]^T, bf16 A/W, bf16 C.
// ---------------------------------------------------------------------------
__global__ __launch_bounds__(256) void gemm_bt64(const bf16_t* __restrict__ A,
                                                 const bf16_t* __restrict__ W,
                                                 bf16_t* __restrict__ C,
                                                 int M, int N, int K) {
  __shared__ bf16_t As[64 * 40];
  __shared__ bf16_t Ws[64 * 40];
  const int tid = threadIdx.x;
  const int bm = blockIdx.y * 64;
  const int bn = blockIdx.x * 64;
  const int wave = tid >> 6, lane = tid & 63;
  const int wm = (wave >> 1) * 32, wn = (wave & 1) * 32;
  const int srow = tid >> 2;
  const int scol = (tid & 3) * 8;
  const bf16_t* Ap16 = A + (size_t)(bm + srow) * K + scol;
  const bf16_t* Wp = W + (size_t)(bn + srow) * K + scol;
  f32x4 acc00 = {}, acc01 = {}, acc10 = {}, acc11 = {};
  const int r = lane & 15;
  const int kq = (lane >> 4) * 8;
  for (int k0 = 0; k0 < K; k0 += 32) {
    *(bf16x8*)&As[srow * 40 + scol] = *(const bf16x8*)(Ap16 + k0);
    *(bf16x8*)&Ws[srow * 40 + scol] = *(const bf16x8*)(Wp + k0);
    __syncthreads();
    bf16x8 a0 = *(bf16x8*)&As[(wm + r) * 40 + kq];
    bf16x8 a1 = *(bf16x8*)&As[(wm + 16 + r) * 40 + kq];
    bf16x8 b0 = *(bf16x8*)&Ws[(wn + r) * 40 + kq];
    bf16x8 b1 = *(bf16x8*)&Ws[(wn + 16 + r) * 40 + kq];
    acc00 = __builtin_amdgcn_mfma_f32_16x16x32_bf16(a0, b0, acc00, 0, 0, 0);
    acc01 = __builtin_amdgcn_mfma_f32_16x16x32_bf16(a0, b1, acc01, 0, 0, 0);
    acc10 = __builtin_amdgcn_mfma_f32_16x16x32_bf16(a1, b0, acc10, 0, 0, 0);
    acc11 = __builtin_amdgcn_mfma_f32_16x16x32_bf16(a1, b1, acc11, 0, 0, 0);
    __syncthreads();
  }
  const int col = lane & 15;
  const int rb = (lane >> 4) * 4;
#pragma unroll
  for (int rr = 0; rr < 4; rr++) {
    int m0r = bm + wm + rb + rr;
    int m1r = m0r + 16;
    C[(size_t)m0r * N + (bn + wn + col)]      = (bf16_t)acc00[rr];
    C[(size_t)m0r * N + (bn + wn + 16 + col)] = (bf16_t)acc01[rr];
    C[(size_t)m1r * N + (bn + wn + col)]      = (bf16_t)acc10[rr];
    C[(size_t)m1r * N + (bn + wn + 16 + col)] = (bf16_t)acc11[rr];
  }
}

// ---------------------------------------------------------------------------
// RMSNorm (bf16 in/out, fp32 math). w is fp32 (original input weight).
// ---------------------------------------------------------------------------
__global__ __launch_bounds__(256) void rmsnorm_k(const bf16_t* __restrict__ x,
                                                 const float* __restrict__ w,
                                                 bf16_t* __restrict__ y,
                                                 int dim, int xstride) {
  const int row = blockIdx.x;
  const bf16_t* xr = x + (size_t)row * xstride;
  bf16_t* yr = y + (size_t)row * dim;
  float ss = 0.f;
  for (int i = threadIdx.x; i < dim; i += 256) {
    float v = (float)xr[i];
    ss += v * v;
  }
  for (int off = 32; off > 0; off >>= 1) ss += __shfl_down(ss, off);
  __shared__ float red[4];
  __shared__ float s_rinv;
  if ((threadIdx.x & 63) == 0) red[threadIdx.x >> 6] = ss;
  __syncthreads();
  if (threadIdx.x == 0) {
    float tot = red[0] + red[1] + red[2] + red[3];
    s_rinv = 1.0f / sqrtf(tot / (float)dim + EPS_);
  }
  __syncthreads();
  float rinv = s_rinv;
  for (int i = threadIdx.x; i < dim; i += 256)
    yr[i] = (bf16_t)((float)xr[i] * rinv * w[i]);
}

// ---------------------------------------------------------------------------
// RoPE with deinterleave. One 64-thread block per 64-elem rope row.
// ---------------------------------------------------------------------------
__global__ __launch_bounds__(64) void rope_k(const bf16_t* __restrict__ src,
                                             bf16_t* __restrict__ dst,
                                             const int* __restrict__ pos_ids,
                                             int heads_per_pos, int sstride,
                                             int dstride) {
  __shared__ float xs[64];
  const int rrow = blockIdx.x;
  const int j = threadIdx.x;
  const bf16_t* s = src + (size_t)rrow * sstride;
  xs[j] = (float)s[j];
  __syncthreads();
  const int pos = pos_ids[rrow / heads_per_pos];
  const int i = j & 31;
  float freq = powf(10000.0f, -(float)i / 32.0f);
  float ang = (float)pos * freq;
  float c = cosf(ang), sn = sinf(ang);
  float outv;
  if (j < 32)
    outv = xs[2 * j] * c - xs[2 * j + 1] * sn;
  else
    outv = xs[2 * i + 1] * c + xs[2 * i] * sn;
  dst[(size_t)rrow * dstride + j] = (bf16_t)outv;
}

// ---------------------------------------------------------------------------
// MFMA causal flash attention (unchanged from verified round-1 version).
// Block = 256 thr (4 waves). Q-block = 128 rows. K-tile = 64.
// ---------------------------------------------------------------------------
__global__ __launch_bounds__(256, 2) void flash_attn2(
    const bf16_t* __restrict__ q, const bf16_t* __restrict__ knope,
    const bf16_t* __restrict__ kpe, const bf16_t* __restrict__ vT,
    bf16_t* __restrict__ attn) {
  __shared__ bf16_t KF[12288];  // [t:4][ks:6][g:4][ll:16][j:8]  24KB
  __shared__ bf16_t VF[8192];   // [dt:8][ks2:2][g:4][ll:16][j:8] 16KB
  __shared__ bf16_t PF[8192];   // per-wave 2048: [qs:2][ks2:2][g:4][ll:16][j:8]
  const int tid = threadIdx.x;
  const int w = tid >> 6;
  const int lane = tid & 63;
  const int ll = lane & 15;
  const int g0 = lane >> 4;
  const int bh = blockIdx.y;
  const int b = bh >> 5;   // / H_
  const int h = bh & 31;   // % H_
  const int q0 = ((int)gridDim.x - 1 - (int)blockIdx.x) * 128;  // heavy blocks first
  const int bS = b * S_;
  bf16_t* PFw = PF + w * 2048;

  bf16x8 qf[2][6];
#pragma unroll
  for (int qs = 0; qs < 2; qs++)
#pragma unroll
    for (int ks = 0; ks < 6; ks++)
      qf[qs][ks] = *(const bf16x8*)(
          q + (((size_t)(bS + q0 + 32 * w + 16 * qs + ll)) * H_ + h) * D_Q_ +
          32 * ks + 8 * g0);

  f32x4 acc[2][8];
#pragma unroll
  for (int qs = 0; qs < 2; qs++)
#pragma unroll
    for (int dt = 0; dt < 8; dt++) acc[qs][dt] = {};
  float m_run[2] = {-1e30f, -1e30f};
  float l_run[2] = {0.f, 0.f};

  const bf16_t* kptr[6];
  int kstr[6];
#pragma unroll
  for (int i = 0; i < 6; i++) {
    int c = tid + 256 * i;
    int t_ = c / 384;
    int rem = c - t_ * 384;
    int ks_ = rem >> 6;
    int g_ = (rem >> 4) & 3;
    int ll_ = c & 15;
    int row = 16 * t_ + ll_;
    int k = 32 * ks_ + 8 * g_;
    if (k < 128) {
      kptr[i] = knope + ((size_t)(bS + row) * H_ + h) * 128 + k;
      kstr[i] = H_ * 128;
    } else {
      kptr[i] = kpe + (size_t)(bS + row) * 64 + (k - 128);
      kstr[i] = 64;
    }
  }
  const bf16_t* vptr[4];
#pragma unroll
  for (int i = 0; i < 4; i++) {
    int c = tid + 256 * i;
    int ll_ = c & 15;
    int g_ = (c >> 4) & 3;
    int ks2_ = (c >> 6) & 1;
    int dt_ = c >> 7;
    vptr[i] = vT + (((size_t)b * H_ + h) * 128 + 16 * dt_ + ll_) * S_ +
              32 * ks2_ + 8 * g_;
  }

  bf16x8 kst[6], vst[4];
  auto load_kv = [&]() {
#pragma unroll
    for (int i = 0; i < 6; i++) kst[i] = *(const bf16x8*)kptr[i];
#pragma unroll
    for (int i = 0; i < 4; i++) vst[i] = *(const bf16x8*)vptr[i];
#pragma unroll
    for (int i = 0; i < 6; i++) kptr[i] += (size_t)64 * kstr[i];
#pragma unroll
    for (int i = 0; i < 4; i++) vptr[i] += 64;
  };

  load_kv();  // tile 0
  const int nkt = (q0 >> 6) + 2;
  const float scale = 0.07216878364870322f;  // 192^-0.5

  for (int kt = 0; kt < nkt; kt++) {
    const int k0 = kt * 64;
    __syncthreads();
#pragma unroll
    for (int i = 0; i < 6; i++) *(bf16x8*)&KF[(tid + 256 * i) * 8] = kst[i];
#pragma unroll
    for (int i = 0; i < 4; i++) *(bf16x8*)&VF[(tid + 256 * i) * 8] = vst[i];
    __syncthreads();
    if (kt + 1 < nkt) load_kv();  // prefetch next tile under compute

    // ---- QK^T (swapped): St[kv][q] ----
    f32x4 sv[2][4];
#pragma unroll
    for (int qs = 0; qs < 2; qs++)
#pragma unroll
      for (int t = 0; t < 4; t++) sv[qs][t] = {};
#pragma unroll
    for (int ks = 0; ks < 6; ks++) {
      bf16x8 bq0 = qf[0][ks], bq1 = qf[1][ks];
#pragma unroll
      for (int t = 0; t < 4; t++) {
        bf16x8 ak = *(bf16x8*)&KF[(t * 6 + ks) * 512 + lane * 8];
        sv[0][t] = __builtin_amdgcn_mfma_f32_16x16x32_bf16(ak, bq0, sv[0][t], 0, 0, 0);
        sv[1][t] = __builtin_amdgcn_mfma_f32_16x16x32_bf16(ak, bq1, sv[1][t], 0, 0, 0);
      }
    }

    // ---- online softmax ----
    float alq[2];
#pragma unroll
    for (int qs = 0; qs < 2; qs++) {
      const int qg = q0 + 32 * w + 16 * qs + ll;
      float mx = m_run[qs];
#pragma unroll
      for (int t = 0; t < 4; t++)
#pragma unroll
        for (int r = 0; r < 4; r++) {
          float s = sv[qs][t][r] * scale;
          int kv = k0 + 16 * t + 4 * g0 + r;
          s = (kv > qg) ? -1e30f : s;
          sv[qs][t][r] = s;
          mx = fmaxf(mx, s);
        }
      mx = fmaxf(mx, __shfl_xor(mx, 16));
      mx = fmaxf(mx, __shfl_xor(mx, 32));
      float al = __expf(m_run[qs] - mx);
      float rs = 0.f;
#pragma unroll
      for (int t = 0; t < 4; t++) {
        bf16x4 pv;
#pragma unroll
        for (int r = 0; r < 4; r++) {
          float p = __expf(sv[qs][t][r] - mx);
          rs += p;
          pv[r] = (bf16_t)p;
        }
        int elem = ((qs * 2 + (t >> 1)) * 4 + 2 * (t & 1) + (g0 >> 1)) * 128 +
                   ll * 8 + 4 * (g0 & 1);
        *(bf16x4*)&PFw[elem] = pv;
      }
      rs += __shfl_xor(rs, 16);
      rs += __shfl_xor(rs, 32);
      l_run[qs] = l_run[qs] * al + rs;
      m_run[qs] = mx;
      alq[qs] = al;
    }

    // ---- rescale O ----
#pragma unroll
    for (int qs = 0; qs < 2; qs++)
#pragma unroll
      for (int r = 0; r < 4; r++) {
        float a = __shfl(alq[qs], 4 * g0 + r);
#pragma unroll
        for (int dt = 0; dt < 8; dt++) acc[qs][dt][r] *= a;
      }

    // ---- PV ----
#pragma unroll
    for (int ks2 = 0; ks2 < 2; ks2++) {
      bf16x8 ap0 = *(bf16x8*)&PFw[ks2 * 512 + lane * 8];
      bf16x8 ap1 = *(bf16x8*)&PFw[(2 + ks2) * 512 + lane * 8];
#pragma unroll
      for (int dt = 0; dt < 8; dt++) {
        bf16x8 bv = *(bf16x8*)&VF[(dt * 2 + ks2) * 512 + lane * 8];
        acc[0][dt] = __builtin_amdgcn_mfma_f32_16x16x32_bf16(ap0, bv, acc[0][dt], 0, 0, 0);
        acc[1][dt] = __builtin_amdgcn_mfma_f32_16x16x32_bf16(ap1, bv, acc[1][dt], 0, 0, 0);
      }
    }
  }

  // ---- epilogue ----
#pragma unroll
  for (int qs = 0; qs < 2; qs++) {
    float linv = 1.f / l_run[qs];
#pragma unroll
    for (int r = 0; r < 4; r++) {
      float inv = __shfl(linv, 4 * g0 + r);
      int qrow = q0 + 32 * w + 16 * qs + 4 * g0 + r;
      bf16_t* op = attn + (((size_t)(bS + qrow)) * H_ + h) * D_V_ + ll;
#pragma unroll
      for (int dt = 0; dt < 8; dt++)
        op[dt * 16] = (bf16_t)(acc[qs][dt][r] * inv);
    }
  }
}

// ---------------------------------------------------------------------------
extern "C" void kernel_launch(void* const* d_in, const int* in_sizes, int n_in,
                              void* d_out, int out_size, void* d_ws, size_t ws_size,
                              hipStream_t stream) {
  const float* hidden  = (const float*)d_in[0];   // [4096,5120] fp32
  const float* q_a_w   = (const float*)d_in[1];   // [1536,5120] fp32
  const float* q_a_ln  = (const float*)d_in[2];   // [1536] fp32
  const float* q_b_w   = (const float*)d_in[3];   // [6144,1536] fp32
  const float* kv_a_w  = (const float*)d_in[4];   // [576,5120] fp32
  const float* kv_a_ln = (const float*)d_in[5];   // [512] fp32
  const float* kv_b_w  = (const float*)d_in[6];   // [8192,512] fp32
  const float* o_w     = (const float*)d_in[7];   // [5120,4096] fp32
  const int*   pos_ids = (const int*)d_in[8];
  // d_in[9] = attention_mask (causal tril) — hardcoded in flash kernel
  float* out = (float*)d_out;                     // [4096,5120] fp32
  char* ws = (char*)d_ws;
  const int M = B_ * S_;  // 4096

  // workspace layout (bytes); Wslot reused for each converted weight.
  bf16_t* q_ws   = (bf16_t*)(ws + 0);            // 4096x6144 bf16 (50.3MB)
  bf16_t* knope_ws=(bf16_t*)(ws + 50331648);     // [B,S,H,128] bf16 (33.6MB)
  bf16_t* vT_ws  = (bf16_t*)(ws + 83886080);     // [B,H,128,S] bf16 (33.6MB)
  bf16_t* kpe_ws = (bf16_t*)(ws + 117440512);    // 4096x64   bf16 (0.5MB)
  bf16_t* Wslot  = (bf16_t*)(ws + 117964800);    // up to 20.97M elems (41.9MB)
  bf16_t* qc_ws  = (bf16_t*)(ws + 159907840);    // 4096x1536 (12.6MB)
  bf16_t* qcn_ws = (bf16_t*)(ws + 172490752);    // 4096x1536 (12.6MB)
  bf16_t* ckv_ws = (bf16_t*)(ws + 185073664);    // 4096x576  (4.7MB)
  bf16_t* ckvn_ws= (bf16_t*)(ws + 189792256);    // 4096x512  (4.2MB) end 193986560
  bf16_t* attn_ws= (bf16_t*)(ws + 159907840);    // 4096x4096 (33.5MB) overlaps qc..ckvn
  // hidden as bf16: overlaps knope/vT region (dead until kv_b gemm; hid_bf
  // dies after the kv_a gemm which precedes kv_b).
  bf16_t* hid_bf = (bf16_t*)(ws + 50331648);     // 4096x5120 bf16 (41.9MB)

  // hidden -> bf16 once
  f32_to_bf16_k<<<(int)((4096L * 5120) / 2048), 256, 0, stream>>>(hidden, hid_bf, 4096L * 5120);
  // q_c = hid @ q_a_w^T
  f32_to_bf16_k<<<1536 * 5120 / 2048, 256, 0, stream>>>(q_a_w, Wslot, 1536L * 5120);
  gemm128<0><<<dim3(1536 / 128, M / 128), 256, 0, stream>>>(hid_bf, Wslot, qc_ws, nullptr, M, 1536, 5120);
  rmsnorm_k<<<M, 256, 0, stream>>>(qc_ws, q_a_ln, qcn_ws, 1536, 1536);
  // ckv = hid @ kv_a_w^T  [b,s,576]  (N=576: legacy 64x64 tile; before q_b so
  // hid_bf's lifetime ends before knope/vT writes)
  f32_to_bf16_k<<<576 * 5120 / 2048, 256, 0, stream>>>(kv_a_w, Wslot, 576L * 5120);
  gemm_bt64<<<dim3(576 / 64, M / 64), 256, 0, stream>>>(hid_bf, Wslot, ckv_ws, M, 576, 5120);
  rmsnorm_k<<<M, 256, 0, stream>>>(ckv_ws, kv_a_ln, ckvn_ws, 512, 576);
  // q = q_cn @ q_b_w^T  [b,s,h,192]
  f32_to_bf16_k<<<6144 * 1536 / 2048, 256, 0, stream>>>(q_b_w, Wslot, 6144L * 1536);
  gemm128<0><<<dim3(6144 / 128, M / 128), 256, 0, stream>>>(qcn_ws, Wslot, q_ws, nullptr, M, 6144, 1536);
  // kv = ckv_n @ kv_b_w^T -> knope[B,S,H,128] + vT[B,H,128,S] (split epilogue)
  f32_to_bf16_k<<<8192 * 512 / 2048, 256, 0, stream>>>(kv_b_w, Wslot, 8192L * 512);
  gemm128<2><<<dim3(8192 / 128, M / 128), 256, 0, stream>>>(ckvn_ws, Wslot, knope_ws, vT_ws, M, 8192, 512);
  // RoPE
  rope_k<<<M * H_, 64, 0, stream>>>(q_ws + 128, q_ws + 128, pos_ids, H_, D_Q_, D_Q_);
  rope_k<<<M, 64, 0, stream>>>(ckv_ws + 512, kpe_ws, pos_ids, 1, 576, 64);
  // MFMA flash attention -> attn_ws [b,s,h,128]
  flash_attn2<<<dim3(S_ / 128, B_ * H_), 256, 0, stream>>>(q_ws, knope_ws, kpe_ws, vT_ws, attn_ws);
  // out = attn @ o_w^T  (fp32 out)
  f32_to_bf16_k<<<5120 * 4096 / 2048, 256, 0, stream>>>(o_w, Wslot, 5120L * 4096);
  gemm128<1><<<dim3(5120 / 128, M / 128), 256, 0, stream>>>(attn_ws, Wslot, out, nullptr, M, 5120, 4096);
}

// Round 3
// 1238.988 us; speedup vs baseline: 4.8478x; 1.0338x over previous
//
#include <hip/hip_runtime.h>
#include <hip/hip_bf16.h>

typedef __bf16 bf16_t;
typedef __bf16 bf16x4 __attribute__((ext_vector_type(4)));
typedef __bf16 bf16x8 __attribute__((ext_vector_type(8)));
typedef float f32x4 __attribute__((ext_vector_type(4)));

#define B_ 2
#define S_ 2048
#define HID_ 5120
#define H_ 32
#define D_NOPE_ 128
#define D_ROPE_ 64
#define D_V_ 128
#define D_Q_ 192
#define EPS_ 1e-6f

// async global->LDS, 16B per lane, linear LDS dest (wave-uniform base + lane*16)
#define GLDS16(g, l)                                                          \
  __builtin_amdgcn_global_load_lds(                                           \
      (const __attribute__((address_space(1))) void*)(g),                     \
      (__attribute__((address_space(3))) void*)(l), 16, 0, 0)

// ---------------------------------------------------------------------------
// fp32 -> bf16 cast, 8 elems/thread. n must be divisible by 2048 (all are).
// ---------------------------------------------------------------------------
__global__ __launch_bounds__(256) void f32_to_bf16_k(const float* __restrict__ x,
                                                     bf16_t* __restrict__ y, long n) {
  long i = ((long)blockIdx.x * 256 + threadIdx.x) * 8;
  if (i + 8 <= n) {
    float4 f0 = *(const float4*)(x + i);
    float4 f1 = *(const float4*)(x + i + 4);
    bf16x8 o;
    o[0] = (bf16_t)f0.x; o[1] = (bf16_t)f0.y; o[2] = (bf16_t)f0.z; o[3] = (bf16_t)f0.w;
    o[4] = (bf16_t)f1.x; o[5] = (bf16_t)f1.y; o[6] = (bf16_t)f1.z; o[7] = (bf16_t)f1.w;
    *(bf16x8*)(y + i) = o;
  }
}

// ---------------------------------------------------------------------------
// gemm128: C[M,N] = A[M,K] @ W[N,K]^T, bf16 in, fp32 MFMA accumulate.
// m97 structure: 128x128 tile, BK=32, 256 thr (4 waves 2x2, each 64x64 =
// 4x4 16x16x32 frags), LDS staged with global_load_lds dwordx4 (linear dest),
// 2 barriers per K-step. M,N % 128 == 0, K % 32 == 0.
// CMODE: 0 = bf16 C; 1 = fp32 C; 2 = split-kv epilogue:
//   n -> (h = n/256, c = n%256); c<128 -> knope[B,S,H,128] (Cv);
//   c>=128 -> vT[B,H,128,S] (vTp) i.e. V stored transposed for flash PV.
// ---------------------------------------------------------------------------
template <int CMODE>
__global__ __launch_bounds__(256) void gemm128(const bf16_t* __restrict__ A,
                                               const bf16_t* __restrict__ W,
                                               void* __restrict__ Cv,
                                               bf16_t* __restrict__ vTp,
                                               int M, int N, int K) {
  __shared__ bf16_t As[128 * 32];
  __shared__ bf16_t Ws[128 * 32];
  const int tid = threadIdx.x;
  const int lane = tid & 63;
  const int wave = tid >> 6;
  const int bm = blockIdx.y * 128;
  const int bn = blockIdx.x * 128;
  const int wm = (wave >> 1) * 64;
  const int wn = (wave & 1) * 64;
  const int ll = lane & 15;
  const int kg = (lane >> 4) * 8;
  const int r0 = tid >> 2;
  const int cc0 = (tid & 3) * 8;
  const bf16_t* Ag0 = A + (size_t)(bm + r0) * K + cc0;
  const bf16_t* Ag1 = A + (size_t)(bm + 64 + r0) * K + cc0;
  const bf16_t* Wg0 = W + (size_t)(bn + r0) * K + cc0;
  const bf16_t* Wg1 = W + (size_t)(bn + 64 + r0) * K + cc0;
  bf16_t* Al0 = &As[tid * 8];
  bf16_t* Al1 = &As[(tid + 256) * 8];
  bf16_t* Wl0 = &Ws[tid * 8];
  bf16_t* Wl1 = &Ws[(tid + 256) * 8];

  f32x4 acc[4][4];
#pragma unroll
  for (int m = 0; m < 4; m++)
#pragma unroll
    for (int n = 0; n < 4; n++) acc[m][n] = {};

  for (int k0 = 0; k0 < K; k0 += 32) {
    GLDS16(Ag0 + k0, Al0);
    GLDS16(Ag1 + k0, Al1);
    GLDS16(Wg0 + k0, Wl0);
    GLDS16(Wg1 + k0, Wl1);
    __syncthreads();  // drains vmcnt -> LDS tile ready
    bf16x8 af[4], bfr[4];
#pragma unroll
    for (int m = 0; m < 4; m++)
      af[m] = *(const bf16x8*)&As[(wm + m * 16 + ll) * 32 + kg];
#pragma unroll
    for (int n = 0; n < 4; n++)
      bfr[n] = *(const bf16x8*)&Ws[(wn + n * 16 + ll) * 32 + kg];
#pragma unroll
    for (int m = 0; m < 4; m++)
#pragma unroll
      for (int n = 0; n < 4; n++)
        acc[m][n] = __builtin_amdgcn_mfma_f32_16x16x32_bf16(af[m], bfr[n], acc[m][n], 0, 0, 0);
    __syncthreads();  // all reads done before next tile's DMA lands
  }

  const int rb = (lane >> 4) * 4;
  if constexpr (CMODE == 2) {
    bf16_t* KN = (bf16_t*)Cv;
#pragma unroll
    for (int m = 0; m < 4; m++)
#pragma unroll
      for (int n = 0; n < 4; n++) {
        int mrow = bm + wm + m * 16 + rb;
        int nn = bn + wn + n * 16 + ll;
        int hh = nn >> 8, cc = nn & 255;
        if (cc < 128) {
          bf16_t* p = KN + ((size_t)mrow * H_ + hh) * 128 + cc;
#pragma unroll
          for (int rr = 0; rr < 4; rr++)
            p[(size_t)rr * (H_ * 128)] = (bf16_t)acc[m][n][rr];
        } else {
          int bb = mrow >> 11;   // / S_
          int s0 = mrow & 2047;  // % S_
          bf16x4 o;
          o[0] = (bf16_t)acc[m][n][0]; o[1] = (bf16_t)acc[m][n][1];
          o[2] = (bf16_t)acc[m][n][2]; o[3] = (bf16_t)acc[m][n][3];
          *(bf16x4*)(vTp + (((size_t)bb * H_ + hh) * 128 + (cc - 128)) * S_ + s0) = o;
        }
      }
  } else {
#pragma unroll
    for (int m = 0; m < 4; m++)
#pragma unroll
      for (int n = 0; n < 4; n++) {
        int row = bm + wm + m * 16 + rb;
        int col = bn + wn + n * 16 + ll;
        if (CMODE == 1) {
          float* C = (float*)Cv;
#pragma unroll
          for (int rr = 0; rr < 4; rr++)
            C[(size_t)(row + rr) * N + col] = acc[m][n][rr];
        } else {
          bf16_t* C = (bf16_t*)Cv;
#pragma unroll
          for (int rr = 0; rr < 4; rr++)
            C[(size_t)(row + rr) * N + col] = (bf16_t)acc[m][n][rr];
        }
      }
  }
}

// ---------------------------------------------------------------------------
// Legacy 64x64 GEMM (used only for kv_a: N=576 not divisible by 128).
// ---------------------------------------------------------------------------
__global__ __launch_bounds__(256) void gemm_bt64(const bf16_t* __restrict__ A,
                                                 const bf16_t* __restrict__ W,
                                                 bf16_t* __restrict__ C,
                                                 int M, int N, int K) {
  __shared__ bf16_t As[64 * 40];
  __shared__ bf16_t Ws[64 * 40];
  const int tid = threadIdx.x;
  const int bm = blockIdx.y * 64;
  const int bn = blockIdx.x * 64;
  const int wave = tid >> 6, lane = tid & 63;
  const int wm = (wave >> 1) * 32, wn = (wave & 1) * 32;
  const int srow = tid >> 2;
  const int scol = (tid & 3) * 8;
  const bf16_t* Ap16 = A + (size_t)(bm + srow) * K + scol;
  const bf16_t* Wp = W + (size_t)(bn + srow) * K + scol;
  f32x4 acc00 = {}, acc01 = {}, acc10 = {}, acc11 = {};
  const int r = lane & 15;
  const int kq = (lane >> 4) * 8;
  for (int k0 = 0; k0 < K; k0 += 32) {
    *(bf16x8*)&As[srow * 40 + scol] = *(const bf16x8*)(Ap16 + k0);
    *(bf16x8*)&Ws[srow * 40 + scol] = *(const bf16x8*)(Wp + k0);
    __syncthreads();
    bf16x8 a0 = *(bf16x8*)&As[(wm + r) * 40 + kq];
    bf16x8 a1 = *(bf16x8*)&As[(wm + 16 + r) * 40 + kq];
    bf16x8 b0 = *(bf16x8*)&Ws[(wn + r) * 40 + kq];
    bf16x8 b1 = *(bf16x8*)&Ws[(wn + 16 + r) * 40 + kq];
    acc00 = __builtin_amdgcn_mfma_f32_16x16x32_bf16(a0, b0, acc00, 0, 0, 0);
    acc01 = __builtin_amdgcn_mfma_f32_16x16x32_bf16(a0, b1, acc01, 0, 0, 0);
    acc10 = __builtin_amdgcn_mfma_f32_16x16x32_bf16(a1, b0, acc10, 0, 0, 0);
    acc11 = __builtin_amdgcn_mfma_f32_16x16x32_bf16(a1, b1, acc11, 0, 0, 0);
    __syncthreads();
  }
  const int col = lane & 15;
  const int rb = (lane >> 4) * 4;
#pragma unroll
  for (int rr = 0; rr < 4; rr++) {
    int m0r = bm + wm + rb + rr;
    int m1r = m0r + 16;
    C[(size_t)m0r * N + (bn + wn + col)]      = (bf16_t)acc00[rr];
    C[(size_t)m0r * N + (bn + wn + 16 + col)] = (bf16_t)acc01[rr];
    C[(size_t)m1r * N + (bn + wn + col)]      = (bf16_t)acc10[rr];
    C[(size_t)m1r * N + (bn + wn + 16 + col)] = (bf16_t)acc11[rr];
  }
}

// ---------------------------------------------------------------------------
// RMSNorm (bf16 in/out, fp32 math). w is fp32 (original input weight).
// ---------------------------------------------------------------------------
__global__ __launch_bounds__(256) void rmsnorm_k(const bf16_t* __restrict__ x,
                                                 const float* __restrict__ w,
                                                 bf16_t* __restrict__ y,
                                                 int dim, int xstride) {
  const int row = blockIdx.x;
  const bf16_t* xr = x + (size_t)row * xstride;
  bf16_t* yr = y + (size_t)row * dim;
  float ss = 0.f;
  for (int i = threadIdx.x; i < dim; i += 256) {
    float v = (float)xr[i];
    ss += v * v;
  }
  for (int off = 32; off > 0; off >>= 1) ss += __shfl_down(ss, off);
  __shared__ float red[4];
  __shared__ float s_rinv;
  if ((threadIdx.x & 63) == 0) red[threadIdx.x >> 6] = ss;
  __syncthreads();
  if (threadIdx.x == 0) {
    float tot = red[0] + red[1] + red[2] + red[3];
    s_rinv = 1.0f / sqrtf(tot / (float)dim + EPS_);
  }
  __syncthreads();
  float rinv = s_rinv;
  for (int i = threadIdx.x; i < dim; i += 256)
    yr[i] = (bf16_t)((float)xr[i] * rinv * w[i]);
}

// ---------------------------------------------------------------------------
// RoPE with deinterleave. One 64-thread block per 64-elem rope row.
// Fast trig: freq = 2^(-i*log2(1e4)/32); __sincosf (HW v_sin/v_cos).
// Max |ang| ~ 2047 rad -> fract-reduction error ~2e-4 << bf16 rounding.
// ---------------------------------------------------------------------------
__global__ __launch_bounds__(64) void rope_k(const bf16_t* __restrict__ src,
                                             bf16_t* __restrict__ dst,
                                             const int* __restrict__ pos_ids,
                                             int heads_per_pos, int sstride,
                                             int dstride) {
  __shared__ float xs[64];
  const int rrow = blockIdx.x;
  const int j = threadIdx.x;
  const bf16_t* s = src + (size_t)rrow * sstride;
  xs[j] = (float)s[j];
  __syncthreads();
  const int pos = pos_ids[rrow / heads_per_pos];
  const int i = j & 31;
  float freq = exp2f(-(float)i * 0.4152410118609203f);  // log2(10000)/32
  float ang = (float)pos * freq;
  float c, sn;
  __sincosf(ang, &sn, &c);
  float outv;
  if (j < 32)
    outv = xs[2 * j] * c - xs[2 * j + 1] * sn;
  else
    outv = xs[2 * i + 1] * c + xs[2 * i] * sn;
  dst[(size_t)rrow * dstride + j] = (bf16_t)outv;
}

// ---------------------------------------------------------------------------
// MFMA causal flash attention, v3: 512 thr / 8 waves, 16 q-rows per wave,
// K-tile = 64. Same HW-verified fragment-major layouts as v2, qs-collapsed
// so per-wave register state halves -> 2 blocks/CU (16 waves/CU).
// Softmax runs in exp2 domain with scale*log2e pre-folded into Q fragments.
// ---------------------------------------------------------------------------
__global__ __launch_bounds__(512, 4) void flash_attn3(
    const bf16_t* __restrict__ q, const bf16_t* __restrict__ knope,
    const bf16_t* __restrict__ kpe, const bf16_t* __restrict__ vT,
    bf16_t* __restrict__ attn) {
  __shared__ bf16_t KF[12288];  // [t:4][ks:6][g:4][ll:16][j:8]  24KB
  __shared__ bf16_t VF[8192];   // [dt:8][ks2:2][g:4][ll:16][j:8] 16KB
  __shared__ bf16_t PF[8192];   // per-wave 1024: [ks2:2][g:4][ll:16][j:8] 16KB
  const int tid = threadIdx.x;
  const int w = tid >> 6;
  const int lane = tid & 63;
  const int ll = lane & 15;
  const int g0 = lane >> 4;
  const int bh = blockIdx.y;
  const int b = bh >> 5;   // / H_
  const int h = bh & 31;   // % H_
  const int q0 = ((int)gridDim.x - 1 - (int)blockIdx.x) * 128;  // heavy blocks first
  const int bS = b * S_;
  bf16_t* PFw = PF + w * 1024;

  // Q fragments, pre-scaled by 192^-0.5 * log2(e): softmax in exp2 domain.
  const float qsc = 0.07216878364870322f * 1.4426950408889634f;
  bf16x8 qf[6];
#pragma unroll
  for (int ks = 0; ks < 6; ks++) {
    bf16x8 raw = *(const bf16x8*)(
        q + (((size_t)(bS + q0 + 16 * w + ll)) * H_ + h) * D_Q_ + 32 * ks + 8 * g0);
    bf16x8 sc;
#pragma unroll
    for (int j = 0; j < 8; j++) sc[j] = (bf16_t)((float)raw[j] * qsc);
    qf[ks] = sc;
  }

  f32x4 acc[8];
#pragma unroll
  for (int dt = 0; dt < 8; dt++) acc[dt] = {};
  float m_run = -1e30f, l_run = 0.f;

  // staging pointers (fragment-major; per-lane source, reg-staged prefetch)
  const bf16_t* kptr[3];
  int kstr[3];
#pragma unroll
  for (int i = 0; i < 3; i++) {
    int c = tid + 512 * i;
    int t_ = c / 384;
    int rem = c - t_ * 384;
    int ks_ = rem >> 6;
    int g_ = (rem >> 4) & 3;
    int ll_ = c & 15;
    int row = 16 * t_ + ll_;
    int k = 32 * ks_ + 8 * g_;
    if (k < 128) {
      kptr[i] = knope + ((size_t)(bS + row) * H_ + h) * 128 + k;
      kstr[i] = H_ * 128;
    } else {
      kptr[i] = kpe + (size_t)(bS + row) * 64 + (k - 128);
      kstr[i] = 64;
    }
  }
  const bf16_t* vptr[2];
#pragma unroll
  for (int i = 0; i < 2; i++) {
    int c = tid + 512 * i;
    int ll_ = c & 15;
    int g_ = (c >> 4) & 3;
    int ks2_ = (c >> 6) & 1;
    int dt_ = c >> 7;
    vptr[i] = vT + (((size_t)b * H_ + h) * 128 + 16 * dt_ + ll_) * S_ +
              32 * ks2_ + 8 * g_;
  }

  bf16x8 kst[3], vst[2];
  auto load_kv = [&]() {
#pragma unroll
    for (int i = 0; i < 3; i++) kst[i] = *(const bf16x8*)kptr[i];
#pragma unroll
    for (int i = 0; i < 2; i++) vst[i] = *(const bf16x8*)vptr[i];
#pragma unroll
    for (int i = 0; i < 3; i++) kptr[i] += (size_t)64 * kstr[i];
#pragma unroll
    for (int i = 0; i < 2; i++) vptr[i] += 64;
  };

  load_kv();  // tile 0
  const int nkt = (q0 >> 6) + 2;

  for (int kt = 0; kt < nkt; kt++) {
    const int k0 = kt * 64;
    __syncthreads();  // previous tile's LDS reads done
#pragma unroll
    for (int i = 0; i < 3; i++) *(bf16x8*)&KF[(tid + 512 * i) * 8] = kst[i];
#pragma unroll
    for (int i = 0; i < 2; i++) *(bf16x8*)&VF[(tid + 512 * i) * 8] = vst[i];
    __syncthreads();
    if (kt + 1 < nkt) load_kv();  // prefetch next tile under compute

    // ---- QK^T (swapped): St[kv][q] ----
    f32x4 sv[4];
#pragma unroll
    for (int t = 0; t < 4; t++) sv[t] = {};
    __builtin_amdgcn_s_setprio(1);
#pragma unroll
    for (int ks = 0; ks < 6; ks++) {
      bf16x8 bq = qf[ks];
#pragma unroll
      for (int t = 0; t < 4; t++) {
        bf16x8 ak = *(bf16x8*)&KF[(t * 6 + ks) * 512 + lane * 8];
        sv[t] = __builtin_amdgcn_mfma_f32_16x16x32_bf16(ak, bq, sv[t], 0, 0, 0);
      }
    }
    __builtin_amdgcn_s_setprio(0);

    // ---- online softmax (exp2 domain; lane owns q = ll) ----
    const int qg = q0 + 16 * w + ll;
    float mx = m_run;
    if (k0 + 63 > q0 + 16 * w) {  // wave-uniform: tile touches the diagonal
#pragma unroll
      for (int t = 0; t < 4; t++)
#pragma unroll
        for (int r = 0; r < 4; r++) {
          float s = sv[t][r];
          s = (k0 + 16 * t + 4 * g0 + r > qg) ? -1e30f : s;
          sv[t][r] = s;
          mx = fmaxf(mx, s);
        }
    } else {  // fully unmasked tile: skip 32 cmp+cndmask
#pragma unroll
      for (int t = 0; t < 4; t++)
#pragma unroll
        for (int r = 0; r < 4; r++) mx = fmaxf(mx, sv[t][r]);
    }
    mx = fmaxf(mx, __shfl_xor(mx, 16));
    mx = fmaxf(mx, __shfl_xor(mx, 32));
    float al = exp2f(m_run - mx);
    float rs = 0.f;
#pragma unroll
    for (int t = 0; t < 4; t++) {
      bf16x4 pv;
#pragma unroll
      for (int r = 0; r < 4; r++) {
        float p = exp2f(sv[t][r] - mx);
        rs += p;
        pv[r] = (bf16_t)p;
      }
      int elem = ((t >> 1) * 4 + 2 * (t & 1) + (g0 >> 1)) * 128 + ll * 8 + 4 * (g0 & 1);
      *(bf16x4*)&PFw[elem] = pv;
    }
    rs += __shfl_xor(rs, 16);
    rs += __shfl_xor(rs, 32);
    l_run = l_run * al + rs;
    m_run = mx;

    // ---- rescale O (O rows are q = 4*g0 + r; alpha held by lane 4*g0+r) ----
#pragma unroll
    for (int r = 0; r < 4; r++) {
      float a = __shfl(al, 4 * g0 + r);
#pragma unroll
      for (int dt = 0; dt < 8; dt++) acc[dt][r] *= a;
    }

    // ---- PV: O[q][d] += P @ V ----
    __builtin_amdgcn_s_setprio(1);
#pragma unroll
    for (int ks2 = 0; ks2 < 2; ks2++) {
      bf16x8 ap = *(bf16x8*)&PFw[ks2 * 512 + lane * 8];
#pragma unroll
      for (int dt = 0; dt < 8; dt++) {
        bf16x8 bv = *(bf16x8*)&VF[(dt * 2 + ks2) * 512 + lane * 8];
        acc[dt] = __builtin_amdgcn_mfma_f32_16x16x32_bf16(ap, bv, acc[dt], 0, 0, 0);
      }
    }
    __builtin_amdgcn_s_setprio(0);
  }

  // ---- epilogue: O[q][d] / l[q] ----
  float linv = 1.f / l_run;
#pragma unroll
  for (int r = 0; r < 4; r++) {
    float inv = __shfl(linv, 4 * g0 + r);
    int qrow = q0 + 16 * w + 4 * g0 + r;
    bf16_t* op = attn + (((size_t)(bS + qrow)) * H_ + h) * D_V_ + ll;
#pragma unroll
    for (int dt = 0; dt < 8; dt++)
      op[dt * 16] = (bf16_t)(acc[dt][r] * inv);
  }
}

// ---------------------------------------------------------------------------
extern "C" void kernel_launch(void* const* d_in, const int* in_sizes, int n_in,
                              void* d_out, int out_size, void* d_ws, size_t ws_size,
                              hipStream_t stream) {
  const float* hidden  = (const float*)d_in[0];   // [4096,5120] fp32
  const float* q_a_w   = (const float*)d_in[1];   // [1536,5120] fp32
  const float* q_a_ln  = (const float*)d_in[2];   // [1536] fp32
  const float* q_b_w   = (const float*)d_in[3];   // [6144,1536] fp32
  const float* kv_a_w  = (const float*)d_in[4];   // [576,5120] fp32
  const float* kv_a_ln = (const float*)d_in[5];   // [512] fp32
  const float* kv_b_w  = (const float*)d_in[6];   // [8192,512] fp32
  const float* o_w     = (const float*)d_in[7];   // [5120,4096] fp32
  const int*   pos_ids = (const int*)d_in[8];
  // d_in[9] = attention_mask (causal tril) — hardcoded in flash kernel
  float* out = (float*)d_out;                     // [4096,5120] fp32
  char* ws = (char*)d_ws;
  const int M = B_ * S_;  // 4096

  // workspace layout (bytes); Wslot reused for each converted weight.
  bf16_t* q_ws   = (bf16_t*)(ws + 0);            // 4096x6144 bf16 (50.3MB)
  bf16_t* knope_ws=(bf16_t*)(ws + 50331648);     // [B,S,H,128] bf16 (33.6MB)
  bf16_t* vT_ws  = (bf16_t*)(ws + 83886080);     // [B,H,128,S] bf16 (33.6MB)
  bf16_t* kpe_ws = (bf16_t*)(ws + 117440512);    // 4096x64   bf16 (0.5MB)
  bf16_t* Wslot  = (bf16_t*)(ws + 117964800);    // up to 20.97M elems (41.9MB)
  bf16_t* qc_ws  = (bf16_t*)(ws + 159907840);    // 4096x1536 (12.6MB)
  bf16_t* qcn_ws = (bf16_t*)(ws + 172490752);    // 4096x1536 (12.6MB)
  bf16_t* ckv_ws = (bf16_t*)(ws + 185073664);    // 4096x576  (4.7MB)
  bf16_t* ckvn_ws= (bf16_t*)(ws + 189792256);    // 4096x512  (4.2MB) end 193986560
  bf16_t* attn_ws= (bf16_t*)(ws + 159907840);    // 4096x4096 (33.5MB) overlaps qc..ckvn
  // hidden as bf16: overlaps knope/vT region (dead until kv_b gemm; hid_bf
  // dies after the kv_a gemm which precedes kv_b).
  bf16_t* hid_bf = (bf16_t*)(ws + 50331648);     // 4096x5120 bf16 (41.9MB)

  // hidden -> bf16 once
  f32_to_bf16_k<<<(int)((4096L * 5120) / 2048), 256, 0, stream>>>(hidden, hid_bf, 4096L * 5120);
  // q_c = hid @ q_a_w^T
  f32_to_bf16_k<<<1536 * 5120 / 2048, 256, 0, stream>>>(q_a_w, Wslot, 1536L * 5120);
  gemm128<0><<<dim3(1536 / 128, M / 128), 256, 0, stream>>>(hid_bf, Wslot, qc_ws, nullptr, M, 1536, 5120);
  rmsnorm_k<<<M, 256, 0, stream>>>(qc_ws, q_a_ln, qcn_ws, 1536, 1536);
  // ckv = hid @ kv_a_w^T  [b,s,576]  (N=576: legacy 64x64 tile; before q_b so
  // hid_bf's lifetime ends before knope/vT writes)
  f32_to_bf16_k<<<576 * 5120 / 2048, 256, 0, stream>>>(kv_a_w, Wslot, 576L * 5120);
  gemm_bt64<<<dim3(576 / 64, M / 64), 256, 0, stream>>>(hid_bf, Wslot, ckv_ws, M, 576, 5120);
  rmsnorm_k<<<M, 256, 0, stream>>>(ckv_ws, kv_a_ln, ckvn_ws, 512, 576);
  // q = q_cn @ q_b_w^T  [b,s,h,192]
  f32_to_bf16_k<<<6144 * 1536 / 2048, 256, 0, stream>>>(q_b_w, Wslot, 6144L * 1536);
  gemm128<0><<<dim3(6144 / 128, M / 128), 256, 0, stream>>>(qcn_ws, Wslot, q_ws, nullptr, M, 6144, 1536);
  // kv = ckv_n @ kv_b_w^T -> knope[B,S,H,128] + vT[B,H,128,S] (split epilogue)
  f32_to_bf16_k<<<8192 * 512 / 2048, 256, 0, stream>>>(kv_b_w, Wslot, 8192L * 512);
  gemm128<2><<<dim3(8192 / 128, M / 128), 256, 0, stream>>>(ckvn_ws, Wslot, knope_ws, vT_ws, M, 8192, 512);
  // RoPE
  rope_k<<<M * H_, 64, 0, stream>>>(q_ws + 128, q_ws + 128, pos_ids, H_, D_Q_, D_Q_);
  rope_k<<<M, 64, 0, stream>>>(ckv_ws + 512, kpe_ws, pos_ids, 1, 576, 64);
  // MFMA flash attention v3 -> attn_ws [b,s,h,128]
  flash_attn3<<<dim3(S_ / 128, B_ * H_), 512, 0, stream>>>(q_ws, knope_ws, kpe_ws, vT_ws, attn_ws);
  // out = attn @ o_w^T  (fp32 out)
  f32_to_bf16_k<<<5120 * 4096 / 2048, 256, 0, stream>>>(o_w, Wslot, 5120L * 4096);
  gemm128<1><<<dim3(5120 / 128, M / 128), 256, 0, stream>>>(attn_ws, Wslot, out, nullptr, M, 5120, 4096);
}